// Round 1
// baseline (706.586 us; speedup 1.0000x reference)
//
#include <hip/hip_runtime.h>
#include <math.h>

#define N_NODES 20000
#define N_EDGESC 320000
#define ET (N_EDGESC + N_NODES)   // 340000 incl. self-loops
#define F_IN 128
#define H1 512
#define H2 256
#define N_CLS 40
#define NEG_SLOPE 0.2f

__global__ void zero_int_kernel(int* __restrict__ p, int n) {
    int i = blockIdx.x * blockDim.x + threadIdx.x;
    if (i < n) p[i] = 0;
}

__global__ void count_deg_kernel(const int* __restrict__ ei, int* __restrict__ deg) {
    int e = blockIdx.x * blockDim.x + threadIdx.x;
    if (e >= ET) return;
    int d = (e < N_EDGESC) ? ei[N_EDGESC + e] : (e - N_EDGESC);
    atomicAdd(&deg[d], 1);
}

__global__ __launch_bounds__(1024) void scan_kernel(const int* __restrict__ deg,
                                                    int* __restrict__ rowptr,
                                                    int* __restrict__ writeptr) {
    __shared__ int sums[1024];
    int t = threadIdx.x;
    const int per = (N_NODES + 1023) / 1024;  // 20
    int base = t * per;
    int local = 0;
    for (int i = 0; i < per; ++i) {
        int idx = base + i;
        if (idx < N_NODES) local += deg[idx];
    }
    sums[t] = local;
    __syncthreads();
    // Hillis-Steele inclusive scan
    for (int off = 1; off < 1024; off <<= 1) {
        int add = (t >= off) ? sums[t - off] : 0;
        __syncthreads();
        sums[t] += add;
        __syncthreads();
    }
    int run = sums[t] - local;  // exclusive prefix of this chunk
    for (int i = 0; i < per; ++i) {
        int idx = base + i;
        if (idx < N_NODES) {
            rowptr[idx] = run;
            writeptr[idx] = run;
            run += deg[idx];
        }
    }
    if (t == 1023) rowptr[N_NODES] = sums[1023];
}

__global__ void fill_kernel(const int* __restrict__ ei, int* __restrict__ writeptr,
                            int* __restrict__ csr_src) {
    int e = blockIdx.x * blockDim.x + threadIdx.x;
    if (e >= ET) return;
    int s, d;
    if (e < N_EDGESC) { s = ei[e]; d = ei[N_EDGESC + e]; }
    else { s = d = e - N_EDGESC; }
    int pos = atomicAdd(&writeptr[d], 1);
    csr_src[pos] = s;
}

// C = A(MxK) * B(KxN), fp32, 64x64 tile, BK=32, 256 threads, 4x4 per thread.
// K must be a multiple of 32 (128/512/256 all are).
__global__ __launch_bounds__(256) void gemm64(const float* __restrict__ A,
                                              const float* __restrict__ B,
                                              float* __restrict__ C,
                                              int M, int K, int N) {
    __shared__ float As[32][65];  // As[k][m]
    __shared__ float Bs[32][65];  // Bs[k][n]
    int t = threadIdx.x;
    int tx = t & 15, ty = t >> 4;
    int bm = blockIdx.y * 64, bn = blockIdx.x * 64;
    float acc[4][4] = {};
    for (int k0 = 0; k0 < K; k0 += 32) {
        for (int i = t; i < 64 * 32; i += 256) {
            int m = i >> 5, k = i & 31;
            int gm = bm + m;
            As[k][m] = (gm < M) ? A[(size_t)gm * K + k0 + k] : 0.f;
        }
        for (int i = t; i < 32 * 64; i += 256) {
            int k = i >> 6, n = i & 63;
            int gn = bn + n;
            Bs[k][n] = (gn < N) ? B[(size_t)(k0 + k) * N + gn] : 0.f;
        }
        __syncthreads();
        #pragma unroll
        for (int k = 0; k < 32; ++k) {
            float a[4], b[4];
            #pragma unroll
            for (int i = 0; i < 4; ++i) a[i] = As[k][ty * 4 + i];
            #pragma unroll
            for (int j = 0; j < 4; ++j) b[j] = Bs[k][tx * 4 + j];
            #pragma unroll
            for (int i = 0; i < 4; ++i)
                #pragma unroll
                for (int j = 0; j < 4; ++j) acc[i][j] += a[i] * b[j];
        }
        __syncthreads();
    }
    #pragma unroll
    for (int i = 0; i < 4; ++i) {
        int gm = bm + ty * 4 + i;
        if (gm >= M) continue;
        #pragma unroll
        for (int j = 0; j < 4; ++j) {
            int gn = bn + tx * 4 + j;
            if (gn < N) C[(size_t)gm * N + gn] = acc[i][j];
        }
    }
}

// per-node dot products with a_src / a_dst; one wave per node
template <int DOUT>
__global__ __launch_bounds__(256) void alpha_kernel(const float* __restrict__ h,
                                                    const float* __restrict__ a_s,
                                                    const float* __restrict__ a_d,
                                                    float* __restrict__ out_s,
                                                    float* __restrict__ out_d) {
    int wave = threadIdx.x >> 6, lane = threadIdx.x & 63;
    int node = blockIdx.x * 4 + wave;
    if (node >= N_NODES) return;
    const float* hr = h + (size_t)node * DOUT;
    float ss = 0.f, sd = 0.f;
    for (int c = lane; c < DOUT; c += 64) {
        float v = hr[c];
        ss += v * a_s[c];
        sd += v * a_d[c];
    }
    #pragma unroll
    for (int off = 32; off; off >>= 1) {
        ss += __shfl_xor(ss, off);
        sd += __shfl_xor(sd, off);
    }
    if (lane == 0) { out_s[node] = ss; out_d[node] = sd; }
}

// softmax-attention aggregation over incoming edges; one wave per node
template <int DOUT, bool RELU, bool LSM>
__global__ __launch_bounds__(256) void agg_kernel(const float* __restrict__ h,
                                                  const float* __restrict__ as,
                                                  const float* __restrict__ ad,
                                                  const int* __restrict__ rowptr,
                                                  const int* __restrict__ csr_src,
                                                  const float* __restrict__ bias,
                                                  float* __restrict__ out) {
    constexpr int C = (DOUT + 63) / 64;
    int wave = threadIdx.x >> 6, lane = threadIdx.x & 63;
    int node = blockIdx.x * 4 + wave;
    if (node >= N_NODES) return;
    int beg = rowptr[node], end = rowptr[node + 1];
    float adi = ad[node];

    // pass 1: segment max
    float m = -INFINITY;
    for (int k = beg + lane; k < end; k += 64) {
        float e = as[csr_src[k]] + adi;
        e = (e > 0.f) ? e : e * NEG_SLOPE;
        m = fmaxf(m, e);
    }
    #pragma unroll
    for (int off = 32; off; off >>= 1) m = fmaxf(m, __shfl_xor(m, off));

    // pass 2: denominator
    float den = 0.f;
    for (int k = beg + lane; k < end; k += 64) {
        float e = as[csr_src[k]] + adi;
        e = (e > 0.f) ? e : e * NEG_SLOPE;
        den += expf(e - m);
    }
    #pragma unroll
    for (int off = 32; off; off >>= 1) den += __shfl_xor(den, off);
    float invden = 1.f / den;

    // pass 3: weighted gather-accumulate
    float acc[C];
    #pragma unroll
    for (int c = 0; c < C; ++c) acc[c] = 0.f;
    for (int k = beg; k < end; ++k) {
        int s = csr_src[k];
        float e = as[s] + adi;
        e = (e > 0.f) ? e : e * NEG_SLOPE;
        float alpha = expf(e - m) * invden;
        const float* hr = h + (size_t)s * DOUT;
        #pragma unroll
        for (int c = 0; c < C; ++c) {
            int col = lane * C + c;
            if (DOUT % 64 == 0 || col < DOUT) acc[c] += alpha * hr[col];
        }
    }

    if constexpr (!LSM) {
        #pragma unroll
        for (int c = 0; c < C; ++c) {
            int col = lane * C + c;
            if (DOUT % 64 == 0 || col < DOUT) {
                float v = acc[c] + bias[col];
                if (RELU) v = fmaxf(v, 0.f);
                out[(size_t)node * DOUT + col] = v;
            }
        }
    } else {
        // DOUT = 40, C = 1: value lives in lanes 0..39; fused log_softmax
        float v = (lane < DOUT) ? (acc[0] + bias[lane]) : -INFINITY;
        float mm = v;
        #pragma unroll
        for (int off = 32; off; off >>= 1) mm = fmaxf(mm, __shfl_xor(mm, off));
        float ex = (lane < DOUT) ? expf(v - mm) : 0.f;
        float Z = ex;
        #pragma unroll
        for (int off = 32; off; off >>= 1) Z += __shfl_xor(Z, off);
        if (lane < DOUT) out[(size_t)node * DOUT + lane] = v - mm - logf(Z);
    }
}

extern "C" void kernel_launch(void* const* d_in, const int* in_sizes, int n_in,
                              void* d_out, int out_size, void* d_ws, size_t ws_size,
                              hipStream_t stream) {
    const float* x   = (const float*)d_in[0];
    const int*   ei  = (const int*)d_in[1];
    const float* W1  = (const float*)d_in[2];
    const float* a1s = (const float*)d_in[3];
    const float* a1d = (const float*)d_in[4];
    const float* b1  = (const float*)d_in[5];
    const float* W2  = (const float*)d_in[6];
    const float* a2s = (const float*)d_in[7];
    const float* a2d = (const float*)d_in[8];
    const float* b2  = (const float*)d_in[9];
    const float* W3  = (const float*)d_in[10];
    const float* a3s = (const float*)d_in[11];
    const float* a3d = (const float*)d_in[12];
    const float* b3  = (const float*)d_in[13];
    float* out = (float*)d_out;

    char* ws = (char*)d_ws;
    size_t off = 0;
    auto alloc = [&](size_t bytes) {
        void* p = ws + off;
        off = (off + bytes + 255) & ~(size_t)255;
        return p;
    };
    int*   deg      = (int*)alloc(N_NODES * 4);
    int*   writeptr = (int*)alloc(N_NODES * 4);
    int*   rowptr   = (int*)alloc((N_NODES + 1) * 4);
    int*   csr_src  = (int*)alloc((size_t)ET * 4);
    float* als      = (float*)alloc(N_NODES * 4);
    float* ald      = (float*)alloc(N_NODES * 4);
    float* bufA     = (float*)alloc((size_t)N_NODES * H1 * 4);
    float* bufB     = (float*)alloc((size_t)N_NODES * H1 * 4);

    // --- build CSR by destination (shared across all 3 layers) ---
    zero_int_kernel<<<(N_NODES + 255) / 256, 256, 0, stream>>>(deg, N_NODES);
    count_deg_kernel<<<(ET + 255) / 256, 256, 0, stream>>>(ei, deg);
    scan_kernel<<<1, 1024, 0, stream>>>(deg, rowptr, writeptr);
    fill_kernel<<<(ET + 255) / 256, 256, 0, stream>>>(ei, writeptr, csr_src);

    dim3 blk(256);
    int nodeblocks = (N_NODES + 3) / 4;

    // --- layer 1: x(20000x128) @ W1(128x512) ---
    gemm64<<<dim3((H1 + 63) / 64, (N_NODES + 63) / 64), blk, 0, stream>>>(
        x, W1, bufA, N_NODES, F_IN, H1);
    alpha_kernel<H1><<<nodeblocks, blk, 0, stream>>>(bufA, a1s, a1d, als, ald);
    agg_kernel<H1, true, false><<<nodeblocks, blk, 0, stream>>>(
        bufA, als, ald, rowptr, csr_src, b1, bufB);

    // --- layer 2: y1(20000x512) @ W2(512x256) ---
    gemm64<<<dim3((H2 + 63) / 64, (N_NODES + 63) / 64), blk, 0, stream>>>(
        bufB, W2, bufA, N_NODES, H1, H2);
    alpha_kernel<H2><<<nodeblocks, blk, 0, stream>>>(bufA, a2s, a2d, als, ald);
    agg_kernel<H2, true, false><<<nodeblocks, blk, 0, stream>>>(
        bufA, als, ald, rowptr, csr_src, b2, bufB);

    // --- layer 3: y2(20000x256) @ W3(256x40), fused log_softmax ---
    gemm64<<<dim3(1, (N_NODES + 63) / 64), blk, 0, stream>>>(
        bufB, W3, bufA, N_NODES, H2, N_CLS);
    alpha_kernel<N_CLS><<<nodeblocks, blk, 0, stream>>>(bufA, a3s, a3d, als, ald);
    agg_kernel<N_CLS, false, true><<<nodeblocks, blk, 0, stream>>>(
        bufA, als, ald, rowptr, csr_src, b3, out);
}

// Round 2
// 422.542 us; speedup vs baseline: 1.6722x; 1.6722x over previous
//
#include <hip/hip_runtime.h>
#include <math.h>

#define N_NODES 20000
#define N_EDGESC 320000
#define ET (N_EDGESC + N_NODES)   // 340000 incl. self-loops
#define F_IN 128
#define H1 512
#define H2 256
#define N_CLS 40
#define NEG_SLOPE 0.2f

typedef __attribute__((ext_vector_type(8))) short short8;
typedef __attribute__((ext_vector_type(4))) float floatx4;

__device__ __forceinline__ unsigned short f2bf(float x) {
    unsigned u = __float_as_uint(x);
    unsigned r = (u + 0x7fffu + ((u >> 16) & 1u)) >> 16;  // round-nearest-even
    return (unsigned short)r;
}

// ---------------- CSR build ----------------

__global__ void zero_int_kernel(int* __restrict__ p, int n) {
    int i = blockIdx.x * blockDim.x + threadIdx.x;
    if (i < n) p[i] = 0;
}

__global__ void count_deg_kernel(const int* __restrict__ ei, int* __restrict__ deg) {
    int e = blockIdx.x * blockDim.x + threadIdx.x;
    if (e >= ET) return;
    int d = (e < N_EDGESC) ? ei[N_EDGESC + e] : (e - N_EDGESC);
    atomicAdd(&deg[d], 1);
}

__global__ __launch_bounds__(1024) void scan_kernel(const int* __restrict__ deg,
                                                    int* __restrict__ rowptr,
                                                    int* __restrict__ writeptr) {
    __shared__ int sums[1024];
    int t = threadIdx.x;
    const int per = (N_NODES + 1023) / 1024;  // 20
    int base = t * per;
    int local = 0;
    for (int i = 0; i < per; ++i) {
        int idx = base + i;
        if (idx < N_NODES) local += deg[idx];
    }
    sums[t] = local;
    __syncthreads();
    for (int off = 1; off < 1024; off <<= 1) {
        int add = (t >= off) ? sums[t - off] : 0;
        __syncthreads();
        sums[t] += add;
        __syncthreads();
    }
    int run = sums[t] - local;
    for (int i = 0; i < per; ++i) {
        int idx = base + i;
        if (idx < N_NODES) {
            rowptr[idx] = run;
            writeptr[idx] = run;
            run += deg[idx];
        }
    }
    if (t == 1023) rowptr[N_NODES] = sums[1023];
}

__global__ void fill_kernel(const int* __restrict__ ei, int* __restrict__ writeptr,
                            int* __restrict__ csr_src) {
    int e = blockIdx.x * blockDim.x + threadIdx.x;
    if (e >= ET) return;
    int s, d;
    if (e < N_EDGESC) { s = ei[e]; d = ei[N_EDGESC + e]; }
    else { s = d = e - N_EDGESC; }
    int pos = atomicAdd(&writeptr[d], 1);
    csr_src[pos] = s;
}

// ---------------- casts ----------------

__global__ void cast_bf16_kernel(const float* __restrict__ in, unsigned short* __restrict__ out, int n) {
    int i = blockIdx.x * blockDim.x + threadIdx.x;
    if (i < n) out[i] = f2bf(in[i]);
}

// Wt[n*K+k] = W[k*N+n], cast to bf16
__global__ void castT_kernel(const float* __restrict__ W, unsigned short* __restrict__ Wt,
                             int K, int N) {
    int i = blockIdx.x * blockDim.x + threadIdx.x;
    if (i >= K * N) return;
    int k = i / N, n = i - k * N;
    Wt[n * K + k] = f2bf(W[i]);
}

// ---------------- MFMA GEMM ----------------
// C(MxN fp32) = A(MxK bf16, row-major) * Bt(NxK bf16, row-major == B^T)
// 256 threads = 4 waves; block tile 64x64; BK=32; wave w does rows [16w,16w+16).
#define LDT 40  // padded LDS stride (bf16 elems) for a 32-wide k tile

__global__ __launch_bounds__(256) void gemm_mfma(const unsigned short* __restrict__ A,
                                                 const unsigned short* __restrict__ Bt,
                                                 float* __restrict__ C,
                                                 int M, int K, int N) {
    __shared__ unsigned short As[64 * LDT];
    __shared__ unsigned short Bs[64 * LDT];
    int t = threadIdx.x;
    int wave = t >> 6, lane = t & 63;
    int quad = lane >> 4, l16 = lane & 15;
    int bm = blockIdx.y * 64, bn = blockIdx.x * 64;
    int sr = t >> 2;          // 0..63 tile row for staging
    int sc = (t & 3) * 8;     // k offset within BK

    floatx4 acc[4];
    #pragma unroll
    for (int i = 0; i < 4; ++i) acc[i] = (floatx4){0.f, 0.f, 0.f, 0.f};

    for (int k0 = 0; k0 < K; k0 += 32) {
        uint4 va = {0, 0, 0, 0}, vb = {0, 0, 0, 0};
        int gm = bm + sr;
        if (gm < M) va = *(const uint4*)(A + (size_t)gm * K + k0 + sc);
        int gn = bn + sr;
        if (gn < N) vb = *(const uint4*)(Bt + (size_t)gn * K + k0 + sc);
        *(uint4*)(&As[sr * LDT + sc]) = va;
        *(uint4*)(&Bs[sr * LDT + sc]) = vb;
        __syncthreads();

        short8 a = *(short8*)(&As[(wave * 16 + l16) * LDT + quad * 8]);
        #pragma unroll
        for (int nt = 0; nt < 4; ++nt) {
            short8 b = *(short8*)(&Bs[(nt * 16 + l16) * LDT + quad * 8]);
            acc[nt] = __builtin_amdgcn_mfma_f32_16x16x32_bf16(a, b, acc[nt], 0, 0, 0);
        }
        __syncthreads();
    }

    #pragma unroll
    for (int nt = 0; nt < 4; ++nt) {
        #pragma unroll
        for (int r = 0; r < 4; ++r) {
            int row = bm + wave * 16 + quad * 4 + r;
            int col = bn + nt * 16 + l16;
            if (row < M && col < N) C[(size_t)row * N + col] = acc[nt][r];
        }
    }
}

// ---------------- per-node alpha dots ----------------

template <int DOUT>
__global__ __launch_bounds__(256) void alpha_kernel(const float* __restrict__ h,
                                                    const float* __restrict__ a_s,
                                                    const float* __restrict__ a_d,
                                                    float* __restrict__ out_s,
                                                    float* __restrict__ out_d) {
    int wave = threadIdx.x >> 6, lane = threadIdx.x & 63;
    int node = blockIdx.x * 4 + wave;
    if (node >= N_NODES) return;
    const float* hr = h + (size_t)node * DOUT;
    float ss = 0.f, sd = 0.f;
    for (int c = lane; c < DOUT; c += 64) {
        float v = hr[c];
        ss += v * a_s[c];
        sd += v * a_d[c];
    }
    #pragma unroll
    for (int off = 32; off; off >>= 1) {
        ss += __shfl_xor(ss, off);
        sd += __shfl_xor(sd, off);
    }
    if (lane == 0) { out_s[node] = ss; out_d[node] = sd; }
}

// ---------------- softmax-attention aggregation ----------------
// OUT_BF16: write bf16 (feeds next GEMM). LSM: fused log_softmax (final layer).
template <int DOUT, bool RELU, bool LSM, bool OUT_BF16>
__global__ __launch_bounds__(256) void agg_kernel(const float* __restrict__ h,
                                                  const float* __restrict__ as,
                                                  const float* __restrict__ ad,
                                                  const int* __restrict__ rowptr,
                                                  const int* __restrict__ csr_src,
                                                  const float* __restrict__ bias,
                                                  void* __restrict__ outp) {
    constexpr int C = (DOUT + 63) / 64;
    int wave = threadIdx.x >> 6, lane = threadIdx.x & 63;
    int node = blockIdx.x * 4 + wave;
    if (node >= N_NODES) return;
    int beg = rowptr[node], end = rowptr[node + 1];
    float adi = ad[node];

    float m = -INFINITY;
    for (int k = beg + lane; k < end; k += 64) {
        float e = as[csr_src[k]] + adi;
        e = (e > 0.f) ? e : e * NEG_SLOPE;
        m = fmaxf(m, e);
    }
    #pragma unroll
    for (int off = 32; off; off >>= 1) m = fmaxf(m, __shfl_xor(m, off));

    float den = 0.f;
    for (int k = beg + lane; k < end; k += 64) {
        float e = as[csr_src[k]] + adi;
        e = (e > 0.f) ? e : e * NEG_SLOPE;
        den += expf(e - m);
    }
    #pragma unroll
    for (int off = 32; off; off >>= 1) den += __shfl_xor(den, off);
    float invden = 1.f / den;

    float acc[C];
    #pragma unroll
    for (int c = 0; c < C; ++c) acc[c] = 0.f;
    for (int k = beg; k < end; ++k) {
        int s = csr_src[k];
        float e = as[s] + adi;
        e = (e > 0.f) ? e : e * NEG_SLOPE;
        float alpha = expf(e - m) * invden;
        const float* hr = h + (size_t)s * DOUT;
        if constexpr (C % 4 == 0) {
            #pragma unroll
            for (int q = 0; q < C / 4; ++q) {
                float4 v = *(const float4*)(hr + lane * C + q * 4);
                acc[q * 4 + 0] += alpha * v.x;
                acc[q * 4 + 1] += alpha * v.y;
                acc[q * 4 + 2] += alpha * v.z;
                acc[q * 4 + 3] += alpha * v.w;
            }
        } else {
            #pragma unroll
            for (int c = 0; c < C; ++c) {
                int col = lane * C + c;
                if (col < DOUT) acc[c] += alpha * hr[col];
            }
        }
    }

    if constexpr (!LSM) {
        #pragma unroll
        for (int c = 0; c < C; ++c) {
            int col = lane * C + c;
            if (DOUT % 64 == 0 || col < DOUT) {
                float v = acc[c] + bias[col];
                if (RELU) v = fmaxf(v, 0.f);
                if constexpr (OUT_BF16)
                    ((unsigned short*)outp)[(size_t)node * DOUT + col] = f2bf(v);
                else
                    ((float*)outp)[(size_t)node * DOUT + col] = v;
            }
        }
    } else {
        float v = (lane < DOUT) ? (acc[0] + bias[lane]) : -INFINITY;
        float mm = v;
        #pragma unroll
        for (int off = 32; off; off >>= 1) mm = fmaxf(mm, __shfl_xor(mm, off));
        float ex = (lane < DOUT) ? expf(v - mm) : 0.f;
        float Z = ex;
        #pragma unroll
        for (int off = 32; off; off >>= 1) Z += __shfl_xor(Z, off);
        if (lane < DOUT) ((float*)outp)[(size_t)node * DOUT + lane] = v - mm - logf(Z);
    }
}

// ---------------- launch ----------------

extern "C" void kernel_launch(void* const* d_in, const int* in_sizes, int n_in,
                              void* d_out, int out_size, void* d_ws, size_t ws_size,
                              hipStream_t stream) {
    const float* x   = (const float*)d_in[0];
    const int*   ei  = (const int*)d_in[1];
    const float* W1  = (const float*)d_in[2];
    const float* a1s = (const float*)d_in[3];
    const float* a1d = (const float*)d_in[4];
    const float* b1  = (const float*)d_in[5];
    const float* W2  = (const float*)d_in[6];
    const float* a2s = (const float*)d_in[7];
    const float* a2d = (const float*)d_in[8];
    const float* b2  = (const float*)d_in[9];
    const float* W3  = (const float*)d_in[10];
    const float* a3s = (const float*)d_in[11];
    const float* a3d = (const float*)d_in[12];
    const float* b3  = (const float*)d_in[13];
    float* out = (float*)d_out;

    char* ws = (char*)d_ws;
    size_t off = 0;
    auto alloc = [&](size_t bytes) {
        void* p = ws + off;
        off = (off + bytes + 255) & ~(size_t)255;
        return p;
    };
    int*            deg      = (int*)alloc(N_NODES * 4);
    int*            writeptr = (int*)alloc(N_NODES * 4);
    int*            rowptr   = (int*)alloc((N_NODES + 1) * 4);
    int*            csr_src  = (int*)alloc((size_t)ET * 4);
    float*          als      = (float*)alloc(N_NODES * 4);
    float*          ald      = (float*)alloc(N_NODES * 4);
    unsigned short* xb       = (unsigned short*)alloc((size_t)N_NODES * F_IN * 2);
    unsigned short* w1t      = (unsigned short*)alloc((size_t)H1 * F_IN * 2);
    unsigned short* w2t      = (unsigned short*)alloc((size_t)H2 * H1 * 2);
    unsigned short* w3t      = (unsigned short*)alloc((size_t)N_CLS * H2 * 2);
    float*          hbuf     = (float*)alloc((size_t)N_NODES * H1 * 4);   // fp32 h
    unsigned short* gbuf     = (unsigned short*)alloc((size_t)N_NODES * H1 * 2); // bf16 agg out

    // --- CSR by destination (shared across layers) ---
    zero_int_kernel<<<(N_NODES + 255) / 256, 256, 0, stream>>>(deg, N_NODES);
    count_deg_kernel<<<(ET + 255) / 256, 256, 0, stream>>>(ei, deg);
    scan_kernel<<<1, 1024, 0, stream>>>(deg, rowptr, writeptr);
    fill_kernel<<<(ET + 255) / 256, 256, 0, stream>>>(ei, writeptr, csr_src);

    // --- casts ---
    cast_bf16_kernel<<<((size_t)N_NODES * F_IN + 255) / 256, 256, 0, stream>>>(x, xb, N_NODES * F_IN);
    castT_kernel<<<(F_IN * H1 + 255) / 256, 256, 0, stream>>>(W1, w1t, F_IN, H1);
    castT_kernel<<<(H1 * H2 + 255) / 256, 256, 0, stream>>>(W2, w2t, H1, H2);
    castT_kernel<<<(H2 * N_CLS + 255) / 256, 256, 0, stream>>>(W3, w3t, H2, N_CLS);

    dim3 blk(256);
    int nodeblocks = (N_NODES + 3) / 4;
    int mtiles = (N_NODES + 63) / 64;

    // --- layer 1 ---
    gemm_mfma<<<dim3(H1 / 64, mtiles), blk, 0, stream>>>(xb, w1t, hbuf, N_NODES, F_IN, H1);
    alpha_kernel<H1><<<nodeblocks, blk, 0, stream>>>(hbuf, a1s, a1d, als, ald);
    agg_kernel<H1, true, false, true><<<nodeblocks, blk, 0, stream>>>(
        hbuf, als, ald, rowptr, csr_src, b1, gbuf);

    // --- layer 2 ---
    gemm_mfma<<<dim3(H2 / 64, mtiles), blk, 0, stream>>>(gbuf, w2t, hbuf, N_NODES, H1, H2);
    alpha_kernel<H2><<<nodeblocks, blk, 0, stream>>>(hbuf, a2s, a2d, als, ald);
    agg_kernel<H2, true, false, true><<<nodeblocks, blk, 0, stream>>>(
        hbuf, als, ald, rowptr, csr_src, b2, gbuf);

    // --- layer 3 (N=40, one n-tile) ---
    gemm_mfma<<<dim3(1, mtiles), blk, 0, stream>>>(gbuf, w3t, hbuf, N_NODES, H2, N_CLS);
    alpha_kernel<N_CLS><<<nodeblocks, blk, 0, stream>>>(hbuf, a3s, a3d, als, ald);
    agg_kernel<N_CLS, false, true, false><<<nodeblocks, blk, 0, stream>>>(
        hbuf, als, ald, rowptr, csr_src, b3, out);
}

// Round 3
// 314.365 us; speedup vs baseline: 2.2477x; 1.3441x over previous
//
#include <hip/hip_runtime.h>
#include <math.h>

#define N_NODES 20000
#define N_EDGESC 320000
#define ET (N_EDGESC + N_NODES)   // 340000 incl. self-loops
#define F_IN 128
#define H1 512
#define H2 256
#define N_CLS 40
#define NEG_SLOPE 0.2f

typedef __attribute__((ext_vector_type(8))) short short8;
typedef __attribute__((ext_vector_type(4))) float floatx4;

__device__ __forceinline__ unsigned short f2bf(float x) {
    unsigned u = __float_as_uint(x);
    unsigned r = (u + 0x7fffu + ((u >> 16) & 1u)) >> 16;  // RNE
    return (unsigned short)r;
}
__device__ __forceinline__ float bflo(unsigned v) { return __uint_as_float(v << 16); }
__device__ __forceinline__ float bfhi(unsigned v) { return __uint_as_float(v & 0xffff0000u); }
__device__ __forceinline__ float leaky(float e) { return (e > 0.f) ? e : e * NEG_SLOPE; }

// ---------------- CSR build ----------------

__global__ void zero_int_kernel(int* __restrict__ p, int n) {
    int i = blockIdx.x * blockDim.x + threadIdx.x;
    if (i < n) p[i] = 0;
}

__global__ void count_deg_kernel(const int* __restrict__ ei, int* __restrict__ deg) {
    int e = blockIdx.x * blockDim.x + threadIdx.x;
    if (e >= ET) return;
    int d = (e < N_EDGESC) ? ei[N_EDGESC + e] : (e - N_EDGESC);
    atomicAdd(&deg[d], 1);
}

__global__ __launch_bounds__(1024) void scan_kernel(const int* __restrict__ deg,
                                                    int* __restrict__ rowptr,
                                                    int* __restrict__ writeptr) {
    __shared__ int sums[1024];
    int t = threadIdx.x;
    const int per = (N_NODES + 1023) / 1024;  // 20
    int base = t * per;
    int local = 0;
    for (int i = 0; i < per; ++i) {
        int idx = base + i;
        if (idx < N_NODES) local += deg[idx];
    }
    sums[t] = local;
    __syncthreads();
    for (int off = 1; off < 1024; off <<= 1) {
        int add = (t >= off) ? sums[t - off] : 0;
        __syncthreads();
        sums[t] += add;
        __syncthreads();
    }
    int run = sums[t] - local;
    for (int i = 0; i < per; ++i) {
        int idx = base + i;
        if (idx < N_NODES) {
            rowptr[idx] = run;
            writeptr[idx] = run;
            run += deg[idx];
        }
    }
    if (t == 1023) rowptr[N_NODES] = sums[1023];
}

__global__ void fill_kernel(const int* __restrict__ ei, int* __restrict__ writeptr,
                            int* __restrict__ csr_src) {
    int e = blockIdx.x * blockDim.x + threadIdx.x;
    if (e >= ET) return;
    int s, d;
    if (e < N_EDGESC) { s = ei[e]; d = ei[N_EDGESC + e]; }
    else { s = d = e - N_EDGESC; }
    int pos = atomicAdd(&writeptr[d], 1);
    csr_src[pos] = s;
}

// ---------------- casts ----------------

__global__ void cast_bf16_kernel(const float* __restrict__ in, unsigned short* __restrict__ out, int n) {
    int i = blockIdx.x * blockDim.x + threadIdx.x;
    if (i < n) out[i] = f2bf(in[i]);
}

// Wt[n*K+k] = W[k*N+n], cast to bf16
__global__ void castT_kernel(const float* __restrict__ W, unsigned short* __restrict__ Wt,
                             int K, int N) {
    int i = blockIdx.x * blockDim.x + threadIdx.x;
    if (i >= K * N) return;
    int k = i / N, n = i - k * N;
    Wt[n * K + k] = f2bf(W[i]);
}

// ---------------- MFMA GEMM ----------------
// C(MxN) = A(MxK bf16 row-major) * Bt(NxK bf16 row-major). OUT_BF16: store bf16.
#define LDT 40  // padded LDS stride (bf16) for BK=32

template <bool OUT_BF16>
__global__ __launch_bounds__(256) void gemm_mfma(const unsigned short* __restrict__ A,
                                                 const unsigned short* __restrict__ Bt,
                                                 void* __restrict__ Cp,
                                                 int M, int K, int N) {
    __shared__ unsigned short As[64 * LDT];
    __shared__ unsigned short Bs[64 * LDT];
    int t = threadIdx.x;
    int wave = t >> 6, lane = t & 63;
    int quad = lane >> 4, l16 = lane & 15;
    int bm = blockIdx.y * 64, bn = blockIdx.x * 64;
    int sr = t >> 2;
    int sc = (t & 3) * 8;

    floatx4 acc[4];
    #pragma unroll
    for (int i = 0; i < 4; ++i) acc[i] = (floatx4){0.f, 0.f, 0.f, 0.f};

    for (int k0 = 0; k0 < K; k0 += 32) {
        uint4 va = {0, 0, 0, 0}, vb = {0, 0, 0, 0};
        int gm = bm + sr;
        if (gm < M) va = *(const uint4*)(A + (size_t)gm * K + k0 + sc);
        int gn = bn + sr;
        if (gn < N) vb = *(const uint4*)(Bt + (size_t)gn * K + k0 + sc);
        *(uint4*)(&As[sr * LDT + sc]) = va;
        *(uint4*)(&Bs[sr * LDT + sc]) = vb;
        __syncthreads();

        short8 a = *(short8*)(&As[(wave * 16 + l16) * LDT + quad * 8]);
        #pragma unroll
        for (int nt = 0; nt < 4; ++nt) {
            short8 b = *(short8*)(&Bs[(nt * 16 + l16) * LDT + quad * 8]);
            acc[nt] = __builtin_amdgcn_mfma_f32_16x16x32_bf16(a, b, acc[nt], 0, 0, 0);
        }
        __syncthreads();
    }

    #pragma unroll
    for (int nt = 0; nt < 4; ++nt) {
        #pragma unroll
        for (int r = 0; r < 4; ++r) {
            int row = bm + wave * 16 + quad * 4 + r;
            int col = bn + nt * 16 + l16;
            if (row < M && col < N) {
                if constexpr (OUT_BF16)
                    ((unsigned short*)Cp)[(size_t)row * N + col] = f2bf(acc[nt][r]);
                else
                    ((float*)Cp)[(size_t)row * N + col] = acc[nt][r];
            }
        }
    }
}

// ---------------- per-node alpha dots ----------------

template <int DOUT, bool IN_BF16>
__global__ __launch_bounds__(256) void alpha_kernel(const void* __restrict__ h,
                                                    const float* __restrict__ a_s,
                                                    const float* __restrict__ a_d,
                                                    float* __restrict__ out_s,
                                                    float* __restrict__ out_d) {
    int wave = threadIdx.x >> 6, lane = threadIdx.x & 63;
    int node = blockIdx.x * 4 + wave;
    if (node >= N_NODES) return;
    float ss = 0.f, sd = 0.f;
    if constexpr (IN_BF16) {
        constexpr int C = DOUT / 64;  // 8 or 4
        const unsigned short* hr = (const unsigned short*)h + (size_t)node * DOUT + lane * C;
        float f[C];
        if constexpr (C == 8) {
            uint4 v = *(const uint4*)hr;
            f[0] = bflo(v.x); f[1] = bfhi(v.x); f[2] = bflo(v.y); f[3] = bfhi(v.y);
            f[4] = bflo(v.z); f[5] = bfhi(v.z); f[6] = bflo(v.w); f[7] = bfhi(v.w);
        } else {
            uint2 v = *(const uint2*)hr;
            f[0] = bflo(v.x); f[1] = bfhi(v.x); f[2] = bflo(v.y); f[3] = bfhi(v.y);
        }
        #pragma unroll
        for (int c = 0; c < C; ++c) {
            ss += f[c] * a_s[lane * C + c];
            sd += f[c] * a_d[lane * C + c];
        }
    } else {
        const float* hr = (const float*)h + (size_t)node * DOUT;
        for (int c = lane; c < DOUT; c += 64) {
            float v = hr[c];
            ss += v * a_s[c];
            sd += v * a_d[c];
        }
    }
    #pragma unroll
    for (int off = 32; off; off >>= 1) {
        ss += __shfl_xor(ss, off);
        sd += __shfl_xor(sd, off);
    }
    if (lane == 0) { out_s[node] = ss; out_d[node] = sd; }
}

// ---------------- softmax-attention aggregation ----------------
// One wave per node. Lane-parallel weight computation + shuffle-broadcast
// serial gather loop (only one load in the serial chain), unrolled x2.
template <int DOUT, bool RELU, bool LSM, bool IN_BF16, bool OUT_BF16>
__global__ __launch_bounds__(256) void agg_kernel(const void* __restrict__ h,
                                                  const float* __restrict__ as,
                                                  const float* __restrict__ ad,
                                                  const int* __restrict__ rowptr,
                                                  const int* __restrict__ csr_src,
                                                  const float* __restrict__ bias,
                                                  void* __restrict__ outp) {
    constexpr int C = (DOUT + 63) / 64;
    int wave = threadIdx.x >> 6, lane = threadIdx.x & 63;
    int node = blockIdx.x * 4 + wave;
    if (node >= N_NODES) return;
    int beg = rowptr[node], end = rowptr[node + 1];
    float adi = ad[node];

    // lane's first-chunk edge (covers deg<=64 entirely)
    int k0 = beg + lane;
    bool has0 = k0 < end;
    int sj = has0 ? csr_src[k0] : 0;
    float ej = -INFINITY;
    if (has0) ej = leaky(as[sj] + adi);

    // segment max
    float m = ej;
    for (int k = k0 + 64; k < end; k += 64) m = fmaxf(m, leaky(as[csr_src[k]] + adi));
    #pragma unroll
    for (int off = 32; off; off >>= 1) m = fmaxf(m, __shfl_xor(m, off));

    // denominator
    float den = has0 ? expf(ej - m) : 0.f;
    for (int k = k0 + 64; k < end; k += 64) den += expf(leaky(as[csr_src[k]] + adi) - m);
    #pragma unroll
    for (int off = 32; off; off >>= 1) den += __shfl_xor(den, off);
    float invden = 1.f / den;

    float w = has0 ? expf(ej - m) * invden : 0.f;

    float acc[C];
    #pragma unroll
    for (int c = 0; c < C; ++c) acc[c] = 0.f;

    auto fetch = [&](int s, float* f) {
        if constexpr (IN_BF16) {
            const unsigned short* hr = (const unsigned short*)h + (size_t)s * DOUT + lane * C;
            if constexpr (C == 8) {
                uint4 v = *(const uint4*)hr;
                f[0] = bflo(v.x); f[1] = bfhi(v.x); f[2] = bflo(v.y); f[3] = bfhi(v.y);
                f[4] = bflo(v.z); f[5] = bfhi(v.z); f[6] = bflo(v.w); f[7] = bfhi(v.w);
            } else {
                uint2 v = *(const uint2*)hr;
                f[0] = bflo(v.x); f[1] = bfhi(v.x); f[2] = bflo(v.y); f[3] = bfhi(v.y);
            }
        } else {
            if (lane < DOUT) f[0] = ((const float*)h)[(size_t)s * DOUT + lane];
            else f[0] = 0.f;
        }
    };

    // serial loop over chunk-0 edges via shuffle broadcast, unrolled x2
    int cnt0 = min(64, end - beg);
    {
        int j = 0;
        for (; j + 1 < cnt0; j += 2) {
            int s0 = __shfl(sj, j), s1 = __shfl(sj, j + 1);
            float a0 = __shfl(w, j), a1 = __shfl(w, j + 1);
            float f0[C], f1[C];
            fetch(s0, f0);
            fetch(s1, f1);
            #pragma unroll
            for (int c = 0; c < C; ++c) acc[c] += a0 * f0[c];
            #pragma unroll
            for (int c = 0; c < C; ++c) acc[c] += a1 * f1[c];
        }
        if (j < cnt0) {
            int s0 = __shfl(sj, j);
            float a0 = __shfl(w, j);
            float f0[C];
            fetch(s0, f0);
            #pragma unroll
            for (int c = 0; c < C; ++c) acc[c] += a0 * f0[c];
        }
    }
    // rare: degree > 64
    for (int base = beg + 64; base < end; base += 64) {
        int cnt = min(64, end - base);
        int sx = 0; float wx = 0.f;
        if (lane < cnt) {
            sx = csr_src[base + lane];
            wx = expf(leaky(as[sx] + adi) - m) * invden;
        }
        for (int j = 0; j < cnt; ++j) {
            int s0 = __shfl(sx, j);
            float a0 = __shfl(wx, j);
            float f0[C];
            fetch(s0, f0);
            #pragma unroll
            for (int c = 0; c < C; ++c) acc[c] += a0 * f0[c];
        }
    }

    if constexpr (!LSM) {
        #pragma unroll
        for (int c = 0; c < C; ++c) {
            int col = lane * C + c;
            if (DOUT % 64 == 0 || col < DOUT) {
                float v = acc[c] + bias[col];
                if (RELU) v = fmaxf(v, 0.f);
                if constexpr (OUT_BF16)
                    ((unsigned short*)outp)[(size_t)node * DOUT + col] = f2bf(v);
                else
                    ((float*)outp)[(size_t)node * DOUT + col] = v;
            }
        }
    } else {
        float v = (lane < DOUT) ? (acc[0] + bias[lane]) : -INFINITY;
        float mm = v;
        #pragma unroll
        for (int off = 32; off; off >>= 1) mm = fmaxf(mm, __shfl_xor(mm, off));
        float ex = (lane < DOUT) ? expf(v - mm) : 0.f;
        float Z = ex;
        #pragma unroll
        for (int off = 32; off; off >>= 1) Z += __shfl_xor(Z, off);
        if (lane < DOUT) ((float*)outp)[(size_t)node * DOUT + lane] = v - mm - logf(Z);
    }
}

// ---------------- launch ----------------

extern "C" void kernel_launch(void* const* d_in, const int* in_sizes, int n_in,
                              void* d_out, int out_size, void* d_ws, size_t ws_size,
                              hipStream_t stream) {
    const float* x   = (const float*)d_in[0];
    const int*   ei  = (const int*)d_in[1];
    const float* W1  = (const float*)d_in[2];
    const float* a1s = (const float*)d_in[3];
    const float* a1d = (const float*)d_in[4];
    const float* b1  = (const float*)d_in[5];
    const float* W2  = (const float*)d_in[6];
    const float* a2s = (const float*)d_in[7];
    const float* a2d = (const float*)d_in[8];
    const float* b2  = (const float*)d_in[9];
    const float* W3  = (const float*)d_in[10];
    const float* a3s = (const float*)d_in[11];
    const float* a3d = (const float*)d_in[12];
    const float* b3  = (const float*)d_in[13];
    float* out = (float*)d_out;

    char* ws = (char*)d_ws;
    size_t off = 0;
    auto alloc = [&](size_t bytes) {
        void* p = ws + off;
        off = (off + bytes + 255) & ~(size_t)255;
        return p;
    };
    int*            deg      = (int*)alloc(N_NODES * 4);
    int*            writeptr = (int*)alloc(N_NODES * 4);
    int*            rowptr   = (int*)alloc((N_NODES + 1) * 4);
    int*            csr_src  = (int*)alloc((size_t)ET * 4);
    float*          als      = (float*)alloc(N_NODES * 4);
    float*          ald      = (float*)alloc(N_NODES * 4);
    unsigned short* xb       = (unsigned short*)alloc((size_t)N_NODES * F_IN * 2);
    unsigned short* w1t      = (unsigned short*)alloc((size_t)H1 * F_IN * 2);
    unsigned short* w2t      = (unsigned short*)alloc((size_t)H2 * H1 * 2);
    unsigned short* w3t      = (unsigned short*)alloc((size_t)N_CLS * H2 * 2);
    unsigned short* hb16     = (unsigned short*)alloc((size_t)N_NODES * H1 * 2);  // bf16 h (L1/L2)
    unsigned short* gbuf     = (unsigned short*)alloc((size_t)N_NODES * H1 * 2);  // bf16 agg out
    float*          h3       = (float*)alloc((size_t)N_NODES * N_CLS * 4);        // fp32 h (L3)

    // --- CSR by destination ---
    zero_int_kernel<<<(N_NODES + 255) / 256, 256, 0, stream>>>(deg, N_NODES);
    count_deg_kernel<<<(ET + 255) / 256, 256, 0, stream>>>(ei, deg);
    scan_kernel<<<1, 1024, 0, stream>>>(deg, rowptr, writeptr);
    fill_kernel<<<(ET + 255) / 256, 256, 0, stream>>>(ei, writeptr, csr_src);

    // --- casts ---
    cast_bf16_kernel<<<((size_t)N_NODES * F_IN + 255) / 256, 256, 0, stream>>>(x, xb, N_NODES * F_IN);
    castT_kernel<<<(F_IN * H1 + 255) / 256, 256, 0, stream>>>(W1, w1t, F_IN, H1);
    castT_kernel<<<(H1 * H2 + 255) / 256, 256, 0, stream>>>(W2, w2t, H1, H2);
    castT_kernel<<<(H2 * N_CLS + 255) / 256, 256, 0, stream>>>(W3, w3t, H2, N_CLS);

    dim3 blk(256);
    int nodeblocks = (N_NODES + 3) / 4;
    int mtiles = (N_NODES + 63) / 64;

    // --- layer 1 ---
    gemm_mfma<true><<<dim3(H1 / 64, mtiles), blk, 0, stream>>>(xb, w1t, hb16, N_NODES, F_IN, H1);
    alpha_kernel<H1, true><<<nodeblocks, blk, 0, stream>>>(hb16, a1s, a1d, als, ald);
    agg_kernel<H1, true, false, true, true><<<nodeblocks, blk, 0, stream>>>(
        hb16, als, ald, rowptr, csr_src, b1, gbuf);

    // --- layer 2 ---
    gemm_mfma<true><<<dim3(H2 / 64, mtiles), blk, 0, stream>>>(gbuf, w2t, hb16, N_NODES, H1, H2);
    alpha_kernel<H2, true><<<nodeblocks, blk, 0, stream>>>(hb16, a2s, a2d, als, ald);
    agg_kernel<H2, true, false, true, true><<<nodeblocks, blk, 0, stream>>>(
        hb16, als, ald, rowptr, csr_src, b2, gbuf);

    // --- layer 3 (fp32 h for final accuracy) ---
    gemm_mfma<false><<<dim3(1, mtiles), blk, 0, stream>>>(gbuf, w3t, h3, N_NODES, H2, N_CLS);
    alpha_kernel<N_CLS, false><<<nodeblocks, blk, 0, stream>>>(h3, a3s, a3d, als, ald);
    agg_kernel<N_CLS, false, true, false, false><<<nodeblocks, blk, 0, stream>>>(
        h3, als, ald, rowptr, csr_src, b3, out);
}